// Round 4
// baseline (181.489 us; speedup 1.0000x reference)
//
#include <hip/hip_runtime.h>
#include <hip/hip_bf16.h>

// Problem constants
#define NE      1024
#define ED      64
#define ZTOT    2097152       // 32*64*1024
#define CIN     256
#define COUT    64
#define HW      1024

// d_out layout (floats): z_q_st[ZTOT], loss[1], sampled[32768], min_idx[32768]
#define OFF_LOSS 2097152
#define OFF_SAMP 2097153
#define OFF_IDX  2129921

#define XSTR 68   // LDS leading-dim pad for k_conv

// ---------------------------------------------------------------------------
// k_prep: blocks 0..127 zero sampled; 128..143 codebook norms + contrastive
// partials (64 codes per block, self-contained).
__global__ __launch_bounds__(256) void k_prep(float* __restrict__ out_samp,
                                              const float* __restrict__ emb,
                                              float* __restrict__ enorm,
                                              float* __restrict__ cpart) {
    int bid = blockIdx.x, t = threadIdx.x;
    if (bid < 128) {
        out_samp[bid * 256 + t] = 0.0f;
        return;
    }
    int g = bid - 128;                      // 0..15, 64 codes each
    __shared__ float inv_s[64];
    __shared__ float S[256];
    if (t < 64) {
        int j = g * 64 + t;
        const float* e = emb + (size_t)j * ED;
        float r8[8];
        #pragma unroll
        for (int s = 0; s < 8; s++) { float v = e[s]; r8[s] = v * v; }
        #pragma unroll
        for (int m = 1; m < 8; m++) {
            #pragma unroll
            for (int s = 0; s < 8; s++) { float v = e[8 * m + s]; r8[s] += v * v; }
        }
        float en = ((r8[0] + r8[1]) + (r8[2] + r8[3])) + ((r8[4] + r8[5]) + (r8[6] + r8[7]));
        enorm[j] = en;
        inv_s[t] = 1.0f / sqrtf(en);
    }
    __syncthreads();
    int d = t & 63, q = t >> 6;
    float s = 0.0f;
    #pragma unroll
    for (int m = 0; m < 16; m++) {
        int i = q + 4 * m;
        s = fmaf(emb[(size_t)(g * 64 + i) * ED + d], inv_s[i], s);
    }
    S[t] = s;
    __syncthreads();
    if (t < 64)
        cpart[g * 64 + t] = (S[t] + S[t + 64]) + (S[t + 128] + S[t + 192]);
}

// ---------------------------------------------------------------------------
// k_conv (R2-proven): z[b,o,p] = sum_c W[o,c]*x[b,c,p] + bias[o].
// Per block: one batch, 64-pixel tile; micro 4px x 4o; LDS Xs[c][px], Ws[c][o].
// K strictly sequential (c = 0..255, fma) to match BLAS rounding.
__global__ __launch_bounds__(256) void k_conv(const float* __restrict__ x,
                                              const float* __restrict__ w,
                                              const float* __restrict__ bias,
                                              float* __restrict__ z) {
    __shared__ float Xs[64 * XSTR];
    __shared__ float Ws[64 * XSTR];
    int t  = threadIdx.x;
    int b  = blockIdx.y;
    int p0 = blockIdx.x * 64;
    int pg = t & 15;        // px = 4*pg + i
    int og = t >> 4;        // o  = 4*og + j
    float acc[4][4];
    #pragma unroll
    for (int i = 0; i < 4; i++)
        #pragma unroll
        for (int j = 0; j < 4; j++) acc[i][j] = 0.0f;

    for (int c0 = 0; c0 < CIN; c0 += 64) {
        __syncthreads();
        {
            int u = t & 15, cg2 = t >> 4;
            #pragma unroll
            for (int m = 0; m < 4; m++) {
                int c = cg2 + 16 * m;
                float4 v = *(const float4*)&x[(size_t)(b * CIN + c0 + c) * HW + p0 + 4 * u];
                *(float4*)&Xs[c * XSTR + 4 * u] = v;
            }
            #pragma unroll
            for (int m = 0; m < 4; m++) {
                int o = cg2 + 16 * m;
                float4 v = *(const float4*)&w[o * CIN + c0 + 4 * u];
                Ws[(4 * u + 0) * XSTR + o] = v.x;
                Ws[(4 * u + 1) * XSTR + o] = v.y;
                Ws[(4 * u + 2) * XSTR + o] = v.z;
                Ws[(4 * u + 3) * XSTR + o] = v.w;
            }
        }
        __syncthreads();
        #pragma unroll 8
        for (int k = 0; k < 64; k++) {
            float4 xv = *(const float4*)&Xs[k * XSTR + 4 * pg];
            float4 wv = *(const float4*)&Ws[k * XSTR + 4 * og];
            float xa[4] = {xv.x, xv.y, xv.z, xv.w};
            float wb[4] = {wv.x, wv.y, wv.z, wv.w};
            #pragma unroll
            for (int i = 0; i < 4; i++)
                #pragma unroll
                for (int j = 0; j < 4; j++)
                    acc[i][j] = fmaf(xa[i], wb[j], acc[i][j]);
        }
    }
    #pragma unroll
    for (int j = 0; j < 4; j++) {
        int o = 4 * og + j;
        float bv = bias[o];
        float4 outv;
        outv.x = acc[0][j] + bv;
        outv.y = acc[1][j] + bv;
        outv.z = acc[2][j] + bv;
        outv.w = acc[3][j] + bv;
        *(float4*)&z[(size_t)(b * COUT + o) * HW + p0 + 4 * pg] = outv;
    }
}

// ---------------------------------------------------------------------------
// k_dist: 64 zf-rows/block, all 1024 codes, argmin (first-min) + fused STE.
// z in XOR-swizzled LDS (8 b128/kb), e streamed from global (L2-resident,
// 8 f4-loads/kb), 256 FMA/kb per thread -> VALU-bound, LDS pipe unloaded.
// micro-tile: 8 rows (rg+8i) x 8 codes (cg+32j), 4 passes of 256 codes.
__global__ __launch_bounds__(256, 2) void k_dist(const float* __restrict__ z,
                                                 const float* __restrict__ emb,
                                                 const float* __restrict__ enorm,
                                                 float* __restrict__ out_idx,
                                                 float* __restrict__ out_samp,
                                                 float* __restrict__ out_zq,
                                                 float* __restrict__ ssep) {
    __shared__ float zs[64 * 64];           // 16 KB, [row][k-granule swizzled]
    __shared__ float zn_s[64];
    __shared__ float redd[32 * 64];         // 8 KB
    __shared__ int   redj[32 * 64];         // 8 KB
    __shared__ int   bj_s[64];
    __shared__ float warr[4];
    int t    = threadIdx.x;
    int row0 = blockIdx.x * 64;
    int rg   = t & 7;                       // rows  rg + 8i
    int cg   = t >> 3;                      // codes pass*256 + cg + 32j

    // stage zs swizzled: granule (kb ^ (row & 15))
    {
        int kb = t & 15, rr0 = t >> 4;
        #pragma unroll
        for (int m = 0; m < 4; m++) {
            int rr = rr0 + 16 * m;
            float4 v = *(const float4*)&z[(size_t)(row0 + rr) * 64 + 4 * kb];
            *(float4*)&zs[rr * 64 + 4 * (kb ^ (rr & 15))] = v;
        }
    }
    // zn: numpy-pairwise sum of squares per row
    if (t < 64) {
        const float* zr = z + (size_t)(row0 + t) * 64;
        float r8[8];
        #pragma unroll
        for (int s = 0; s < 8; s++) { float v = zr[s]; r8[s] = v * v; }
        #pragma unroll
        for (int m = 1; m < 8; m++) {
            #pragma unroll
            for (int s = 0; s < 8; s++) { float v = zr[8 * m + s]; r8[s] += v * v; }
        }
        zn_s[t] = ((r8[0] + r8[1]) + (r8[2] + r8[3])) + ((r8[4] + r8[5]) + (r8[6] + r8[7]));
    }
    __syncthreads();

    float znr[8];
    #pragma unroll
    for (int i = 0; i < 8; i++) znr[i] = zn_s[rg + 8 * i];

    float bestd[8];
    int   bestj[8];
    #pragma unroll
    for (int i = 0; i < 8; i++) { bestd[i] = __builtin_huge_valf(); bestj[i] = 0; }

    for (int pass = 0; pass < 4; pass++) {
        float acc[8][8];
        #pragma unroll
        for (int i = 0; i < 8; i++)
            #pragma unroll
            for (int j = 0; j < 8; j++) acc[i][j] = 0.0f;

        const float* ebase = emb + ((size_t)(pass * 256 + cg) << 6);
        for (int kb = 0; kb < 16; kb++) {
            float4 za[8];
            #pragma unroll
            for (int i = 0; i < 8; i++) {
                int rr = rg + 8 * i;
                za[i] = *(const float4*)&zs[rr * 64 + 4 * (kb ^ (rr & 15))];
            }
            #pragma unroll
            for (int j = 0; j < 8; j++) {
                float4 ev = *(const float4*)&ebase[((size_t)(32 * j) << 6) + 4 * kb];
                #pragma unroll
                for (int i = 0; i < 8; i++) {
                    acc[i][j] = fmaf(za[i].x, ev.x, acc[i][j]);
                    acc[i][j] = fmaf(za[i].y, ev.y, acc[i][j]);
                    acc[i][j] = fmaf(za[i].z, ev.z, acc[i][j]);
                    acc[i][j] = fmaf(za[i].w, ev.w, acc[i][j]);
                }
            }
        }
        // d = fl(fl(zn + en) - 2*dot); strict < keeps first (c ascends per thread)
        #pragma unroll
        for (int j = 0; j < 8; j++) {
            int c = pass * 256 + cg + 32 * j;
            float en = enorm[c];
            #pragma unroll
            for (int i = 0; i < 8; i++) {
                float A = znr[i] + en;
                float D = A - 2.0f * acc[i][j];
                if (D < bestd[i]) { bestd[i] = D; bestj[i] = c; }
            }
        }
    }

    #pragma unroll
    for (int i = 0; i < 8; i++) {
        redd[cg * 64 + rg + 8 * i] = bestd[i];
        redj[cg * 64 + rg + 8 * i] = bestj[i];
    }
    __syncthreads();
    if (t < 64) {
        float bd = __builtin_huge_valf();
        int   bj = 0x7fffffff;
        #pragma unroll
        for (int c = 0; c < 32; c++) {
            float dd = redd[c * 64 + t];
            int   jj = redj[c * 64 + t];
            if (dd < bd || (dd == bd && jj < bj)) { bd = dd; bj = jj; }
        }
        bj_s[t] = bj;
        out_idx[row0 + t] = (float)bj;
        atomicExch(&out_samp[bj], 1.0f);    // scattered, low contention
    }
    __syncthreads();

    // Fused STE epilogue from zs (bit-exact z), emb gather, SSE partial.
    {
        int r  = t & 63;
        int kq = t >> 6;                    // k-range [16kq, 16kq+16)
        int bj = bj_s[r];
        const float* er = emb + ((size_t)bj << 6) + kq * 16;
        float sq = 0.0f;
        #pragma unroll
        for (int m = 0; m < 4; m++) {
            int kb = 4 * kq + m;
            float4 zv = *(const float4*)&zs[r * 64 + 4 * (kb ^ (r & 15))];
            float4 ev = *(const float4*)&er[4 * m];
            float d0 = ev.x - zv.x, d1 = ev.y - zv.y, d2 = ev.z - zv.z, d3 = ev.w - zv.w;
            float4 o4;
            o4.x = zv.x + d0; o4.y = zv.y + d1; o4.z = zv.z + d2; o4.w = zv.w + d3;
            *(float4*)&out_zq[((size_t)(row0 + r) << 6) + 4 * kb] = o4;
            sq += d0 * d0; sq += d1 * d1; sq += d2 * d2; sq += d3 * d3;
        }
        #pragma unroll
        for (int off = 32; off > 0; off >>= 1) sq += __shfl_down(sq, off, 64);
        if ((t & 63) == 0) warr[t >> 6] = sq;
    }
    __syncthreads();
    if (t == 0)
        ssep[blockIdx.x] = (warr[0] + warr[1]) + (warr[2] + warr[3]);
}

// ---------------------------------------------------------------------------
// k_final: deterministic combine of 512 SSE partials + 16x64 contrastive.
__global__ __launch_bounds__(256) void k_final(const float* __restrict__ ssep,
                                               const float* __restrict__ cpart,
                                               float* __restrict__ out_loss) {
    __shared__ double SD[256];
    __shared__ float  CS;
    int t = threadIdx.x;
    SD[t] = (double)ssep[t] + (double)ssep[t + 256];
    __syncthreads();
    #pragma unroll
    for (int off = 128; off > 0; off >>= 1) {
        if (t < off) SD[t] += SD[t + off];
        __syncthreads();
    }
    if (t < 64) {
        float v = 0.0f;
        #pragma unroll
        for (int m = 0; m < 16; m++) v += cpart[m * 64 + t];
        float sq = v * v;
        #pragma unroll
        for (int off = 32; off > 0; off >>= 1) sq += __shfl_down(sq, off, 64);
        if (t == 0) CS = sq / (1024.0f * 1024.0f);
    }
    __syncthreads();
    if (t == 0) {
        float m = (float)(SD[0] / (double)ZTOT);
        out_loss[0] = (m + 0.25f * m) + CS;     // LEGACY: mse + BETA*mse
    }
}

// ---------------------------------------------------------------------------
extern "C" void kernel_launch(void* const* d_in, const int* in_sizes, int n_in,
                              void* d_out, int out_size, void* d_ws, size_t ws_size,
                              hipStream_t stream) {
    (void)in_sizes; (void)n_in; (void)out_size; (void)ws_size;
    const float* z_     = (const float*)d_in[0];
    const float* conv_w = (const float*)d_in[1];
    const float* conv_b = (const float*)d_in[2];
    const float* emb    = (const float*)d_in[3];

    float* out      = (float*)d_out;
    float* out_zq   = out;
    float* out_loss = out + OFF_LOSS;
    float* out_samp = out + OFF_SAMP;
    float* out_idx  = out + OFF_IDX;

    char*   ws    = (char*)d_ws;
    float*  wz    = (float*)ws;                 // z, 8 MB
    float*  enorm = (float*)(ws + 8388608);     // 1024
    float*  cpart = enorm + 1024;               // 16*64
    float*  ssep  = cpart + 1024;               // 512

    k_prep <<<144, 256, 0, stream>>>(out_samp, emb, enorm, cpart);
    k_conv <<<dim3(16, 32), 256, 0, stream>>>(z_, conv_w, conv_b, wz);
    k_dist <<<512, 256, 0, stream>>>(wz, emb, enorm, out_idx, out_samp, out_zq, ssep);
    k_final<<<1, 256, 0, stream>>>(ssep, cpart, out_loss);
}